// Round 1
// baseline (27933.707 us; speedup 1.0000x reference)
//
#include <hip/hip_runtime.h>
#include <hip/hip_bf16.h>
#include <hip/hip_cooperative_groups.h>

namespace cg = cooperative_groups;

typedef unsigned short u16;
typedef short  s16x4 __attribute__((ext_vector_type(4)));
typedef short  s16x8 __attribute__((ext_vector_type(8)));
typedef __bf16 bf16x8 __attribute__((ext_vector_type(8)));
typedef float  f32x4 __attribute__((ext_vector_type(4)));

__device__ __forceinline__ u16 f32_to_bf16(float f) {
  unsigned u = __builtin_bit_cast(unsigned, f);
  u += 0x7fffu + ((u >> 16) & 1u);
  return (u16)(u >> 16);
}
__device__ __forceinline__ float bf16_to_f32(u16 b) {
  unsigned u = ((unsigned)b) << 16;
  return __builtin_bit_cast(float, u);
}
__device__ __forceinline__ float sigmoidf_(float x) { return 1.f / (1.f + __expf(-x)); }
__device__ __forceinline__ float tanhf_(float x)    { return 1.f - 2.f / (__expf(2.f * x) + 1.f); }

__device__ __forceinline__ void load_lds16(const void* g, void* l) {
  __builtin_amdgcn_global_load_lds((const __attribute__((address_space(1))) void*)g,
                                   (__attribute__((address_space(3))) void*)l, 16, 0, 0);
}
__device__ __forceinline__ f32x4 mfma_bf16(bf16x8 a, bf16x8 b, f32x4 c) {
  return __builtin_amdgcn_mfma_f32_16x16x32_bf16(a, b, c, 0, 0, 0);
}

// ---------------- prep kernels ----------------

__global__ void cvt_f32_bf16_k(const float* __restrict__ in, u16* __restrict__ out, int n4) {
  int i = blockIdx.x * 256 + threadIdx.x;
  if (i < n4) {
    const float4 v = ((const float4*)in)[i];
    s16x4 o = { (short)f32_to_bf16(v.x), (short)f32_to_bf16(v.y),
                (short)f32_to_bf16(v.z), (short)f32_to_bf16(v.w) };
    *(s16x4*)&out[(size_t)i * 4] = o;
  }
}

// dst[n][k] = src[k][n]  (fp32 -> bf16)
__global__ void transpose_cvt_k(const float* __restrict__ src, u16* __restrict__ dst, int K, int N) {
  int lane = threadIdx.x & 63, wv = threadIdx.x >> 6;
  int n  = blockIdx.x * 64 + lane;
  int k0 = (blockIdx.y * 4 + wv) * 8;
  s16x8 o;
#pragma unroll
  for (int j = 0; j < 8; ++j)
    o[j] = (short)f32_to_bf16(src[(size_t)(k0 + j) * N + n]);
  *(s16x8*)&dst[(size_t)n * K + k0] = o;
}

__global__ void make_bcat_k(const float* bxi, const float* bxf, const float* bxc, const float* bxo,
                            const float* bhi, const float* bhf, const float* bhc, const float* bho,
                            float* bcat) {
  int i = blockIdx.x * 256 + threadIdx.x;  // 0..4095
  int g = i >> 10, h = i & 1023;
  float v;
  if (g == 0)      v = bxi[h] + bhi[h];
  else if (g == 1) v = bxf[h] + bhf[h];
  else if (g == 2) v = bxc[h] + bhc[h];
  else             v = bxo[h] + bho[h];
  bcat[i] = v;
}

// ---------------- tiled bf16 GEMM:  C[M,N] = A[M,K] @ Bt[N,K]^T + bias ----------------
// 128x128 tile, BK=64, 4 waves each computing a 64x64 quadrant.
// LDS unpadded [row][64] with XOR chunk swizzle: slot s of row r holds logical chunk s^(r&7).

template<bool STORE_BF16>
__global__ __launch_bounds__(256, 2)
void gemm_bt(const u16* __restrict__ A, const u16* __restrict__ Bt,
             void* __restrict__ Cout, const float* __restrict__ bias,
             int M, int N, int K)
{
  __shared__ __align__(16) u16 As[128 * 64];
  __shared__ __align__(16) u16 Bs[128 * 64];
  const int tid  = threadIdx.x;
  const int lane = tid & 63;
  const int wv   = tid >> 6;
  const int ntile = blockIdx.x, mtile = blockIdx.y;
  const u16* Ab = A + (size_t)mtile * 128 * K;
  const u16* Bb = Bt + (size_t)ntile * 128 * K;

  const int r8   = lane >> 3;        // staging: row-within-8
  const int slot = lane & 7;         // staging: LDS chunk slot
  const int cgk  = slot ^ r8;        // logical chunk fetched from global
  const int r = lane & 15;
  const int q = lane >> 4;
  const int mbase = (wv & 1) * 64;
  const int nbase = (wv >> 1) * 64;

  f32x4 acc[4][4];
#pragma unroll
  for (int i = 0; i < 4; ++i)
#pragma unroll
    for (int j = 0; j < 4; ++j) acc[i][j] = (f32x4){0.f, 0.f, 0.f, 0.f};

  for (int kb = 0; kb < K; kb += 64) {
    __syncthreads();
#pragma unroll
    for (int j = 0; j < 4; ++j) {
      const int row = wv * 32 + j * 8;  // wave-uniform LDS base row (lane adds r8/slot)
      load_lds16(Ab + (size_t)(row + r8) * K + kb + cgk * 8, &As[row * 64]);
      load_lds16(Bb + (size_t)(row + r8) * K + kb + cgk * 8, &Bs[row * 64]);
    }
    __syncthreads();
#pragma unroll
    for (int kk = 0; kk < 64; kk += 32) {
      const int cbase = (kk >> 3) + q;
      bf16x8 af[4], bf[4];
#pragma unroll
      for (int mi = 0; mi < 4; ++mi) {
        int rr = mbase + mi * 16 + r;
        af[mi] = *(const bf16x8*)&As[rr * 64 + (cbase ^ (rr & 7)) * 8];
      }
#pragma unroll
      for (int ni = 0; ni < 4; ++ni) {
        int rr = nbase + ni * 16 + r;
        bf[ni] = *(const bf16x8*)&Bs[rr * 64 + (cbase ^ (rr & 7)) * 8];
      }
#pragma unroll
      for (int mi = 0; mi < 4; ++mi)
#pragma unroll
        for (int ni = 0; ni < 4; ++ni)
          acc[mi][ni] = mfma_bf16(af[mi], bf[ni], acc[mi][ni]);
    }
  }

#pragma unroll
  for (int mi = 0; mi < 4; ++mi) {
#pragma unroll
    for (int ni = 0; ni < 4; ++ni) {
      const int col = ntile * 128 + nbase + ni * 16 + r;
      const float bv = bias[col];
#pragma unroll
      for (int t2 = 0; t2 < 4; ++t2) {
        const size_t rowg = (size_t)mtile * 128 + mbase + mi * 16 + q * 4 + t2;
        float v = acc[mi][ni][t2] + bv;
        if (STORE_BF16) ((u16*)Cout)[rowg * N + col] = f32_to_bf16(v);
        else            ((float*)Cout)[rowg * N + col] = v;
      }
    }
  }
}

// ---------------- persistent LSTM scan ----------------
// 256 WGs = 4 batch-blocks x 64 dim-blocks. Each WG: 16 batch rows x 16 h-dims.
// LDS: W_h slice as Wt[col][k], col = g*16 + d (gate-major), stride 1032 (+8 pad).
// c-state: 1 fp32 per thread. h history: global bf16 [S+1][64][1024].

__global__ __launch_bounds__(256, 1)
void lstm_scan(const u16* __restrict__ gates_x, u16* __restrict__ h_hist,
               const float* __restrict__ Whi, const float* __restrict__ Whf,
               const float* __restrict__ Whc, const float* __restrict__ Who, int S)
{
  extern __shared__ char smem[];
  u16*   Wt  = (u16*)smem;                    // [64][1032] bf16
  float* pre = (float*)(smem + 64 * 1032 * 2); // [4][16][16]
  const int tid = threadIdx.x, lane = tid & 63, wv = tid >> 6;
  const int bblk = blockIdx.x >> 6;
  const int dblk = blockIdx.x & 63;
  const int dim0 = dblk << 4;
  const int d = tid & 15, b = tid >> 4;

  // load W_h slice -> LDS (coalesced 64B row segments, one-time)
  {
    const int pr = tid >> 4;  // 0..15 -> k strider
    const float* Ws[4] = {Whi, Whf, Whc, Who};
#pragma unroll
    for (int g = 0; g < 4; ++g) {
      const float* W = Ws[g];
      for (int it = 0; it < 64; ++it) {
        int k = it * 16 + pr;
        float v = W[(size_t)k * 1024 + dim0 + d];
        Wt[(g * 16 + d) * 1032 + k] = f32_to_bf16(v);
      }
    }
  }
  // zero h_0 slice; c-state in register
  h_hist[(size_t)(bblk * 16 + b) * 1024 + dim0 + d] = 0;
  float c = 0.f;
  __threadfence();
  cg::this_grid().sync();

  const int r = lane & 15, q = lane >> 4;
  const u16* Brow = Wt + (wv * 16 + r) * 1032 + q * 8;

  for (int t = 0; t < S; ++t) {
    // x-projection gate values for this (b,d) — independent of h, prefetch early
    const u16* gx = gates_x + (size_t)(t * 64 + bblk * 16 + b) * 4096 + dim0 + d;
    float xg0 = bf16_to_f32(gx[0]);
    float xg1 = bf16_to_f32(gx[1024]);
    float xg2 = bf16_to_f32(gx[2048]);
    float xg3 = bf16_to_f32(gx[3072]);

    // wave wv computes gate wv: [16 batch x 16 dim] = h_t[16x1024] @ Wt[16 cols]
    const u16* Arow = h_hist + (size_t)t * 65536 + (size_t)(bblk * 16 + r) * 1024 + q * 8;
    f32x4 a0 = {0.f, 0.f, 0.f, 0.f}, a1 = a0, a2 = a0, a3 = a0;
#pragma unroll
    for (int k = 0; k < 1024; k += 128) {
      a0 = mfma_bf16(*(const bf16x8*)(Arow + k),      *(const bf16x8*)(Brow + k),      a0);
      a1 = mfma_bf16(*(const bf16x8*)(Arow + k + 32), *(const bf16x8*)(Brow + k + 32), a1);
      a2 = mfma_bf16(*(const bf16x8*)(Arow + k + 64), *(const bf16x8*)(Brow + k + 64), a2);
      a3 = mfma_bf16(*(const bf16x8*)(Arow + k + 96), *(const bf16x8*)(Brow + k + 96), a3);
    }
    f32x4 accv = (a0 + a1) + (a2 + a3);
#pragma unroll
    for (int t2 = 0; t2 < 4; ++t2)
      pre[wv * 256 + (q * 4 + t2) * 16 + r] = accv[t2];
    __syncthreads();

    float pi = pre[0 * 256 + b * 16 + d] + xg0;
    float pf = pre[1 * 256 + b * 16 + d] + xg1;
    float pc = pre[2 * 256 + b * 16 + d] + xg2;
    float po = pre[3 * 256 + b * 16 + d] + xg3;
    float ig = sigmoidf_(pi);
    float fg = sigmoidf_(pf);
    float gg = tanhf_(pc);
    float og = sigmoidf_(po);
    c = fg * c + ig * gg;
    float h = og * tanhf_(c);
    h_hist[(size_t)(t + 1) * 65536 + (size_t)(bblk * 16 + b) * 1024 + dim0 + d] = f32_to_bf16(h);
    __threadfence();
    cg::this_grid().sync();
  }
}

// ---------------- launcher ----------------

extern "C" void kernel_launch(void* const* d_in, const int* in_sizes, int n_in,
                              void* d_out, int out_size, void* d_ws, size_t ws_size,
                              hipStream_t stream)
{
  const float* x   = (const float*)d_in[0];
  const float* Wxi = (const float*)d_in[1];
  const float* bxi = (const float*)d_in[2];
  const float* Wxf = (const float*)d_in[3];
  const float* bxf = (const float*)d_in[4];
  const float* Wxc = (const float*)d_in[5];
  const float* bxc = (const float*)d_in[6];
  const float* Wxo = (const float*)d_in[7];
  const float* bxo = (const float*)d_in[8];
  const float* Whi = (const float*)d_in[9];
  const float* bhi = (const float*)d_in[10];
  const float* Whf = (const float*)d_in[11];
  const float* bhf = (const float*)d_in[12];
  const float* Whc = (const float*)d_in[13];
  const float* bhc = (const float*)d_in[14];
  const float* Who = (const float*)d_in[15];
  const float* bho = (const float*)d_in[16];
  const float* Why = (const float*)d_in[17];
  const float* bhy = (const float*)d_in[18];

  char* ws = (char*)d_ws;
  u16*   x_bf   = (u16*)(ws);                 //  67,108,864 B
  u16*   WcatT  = (u16*)(ws + 67108864);      //   8,388,608 B  [4096][1024]
  u16*   WhyT   = (u16*)(ws + 75497472);      //   2,097,152 B  [1024][1024]
  float* bcat   = (float*)(ws + 77594624);    //      16,384 B
  u16*   gatesx = (u16*)(ws + 77611008);      // 268,435,456 B  [32768][4096]
  u16*   hhist  = (u16*)(ws + 346046464);     //  67,239,936 B  [513][64][1024]

  // prep: casts + transposes + fused bias
  cvt_f32_bf16_k<<<32768, 256, 0, stream>>>(x, x_bf, 8388608);
  transpose_cvt_k<<<dim3(16, 32), 256, 0, stream>>>(Wxi, WcatT + 0 * 1048576, 1024, 1024);
  transpose_cvt_k<<<dim3(16, 32), 256, 0, stream>>>(Wxf, WcatT + 1 * 1048576, 1024, 1024);
  transpose_cvt_k<<<dim3(16, 32), 256, 0, stream>>>(Wxc, WcatT + 2 * 1048576, 1024, 1024);
  transpose_cvt_k<<<dim3(16, 32), 256, 0, stream>>>(Wxo, WcatT + 3 * 1048576, 1024, 1024);
  transpose_cvt_k<<<dim3(16, 32), 256, 0, stream>>>(Why, WhyT, 1024, 1024);
  make_bcat_k<<<16, 256, 0, stream>>>(bxi, bxf, bxc, bxo, bhi, bhf, bhc, bho, bcat);

  // phase 1: gates_x = x @ [Wxi|Wxf|Wxc|Wxo] + (b_x + b_h)
  gemm_bt<true><<<dim3(32, 256), 256, 0, stream>>>(x_bf, WcatT, (void*)gatesx, bcat, 32768, 4096, 1024);

  // phase 2: persistent cooperative scan
  (void)hipFuncSetAttribute((const void*)lstm_scan, hipFuncAttributeMaxDynamicSharedMemorySize, 136192);
  int S = 512;
  void* args[] = {(void*)&gatesx, (void*)&hhist, (void*)&Whi, (void*)&Whf, (void*)&Whc, (void*)&Who, (void*)&S};
  (void)hipLaunchCooperativeKernel((void*)lstm_scan, dim3(256), dim3(256), args, 136192, stream);

  // phase 3: y = h_{1..S} @ W_hy + b_hy  (fp32 out)
  gemm_bt<false><<<dim3(8, 256), 256, 0, stream>>>(hhist + 65536, WhyT, d_out, bhy, 32768, 1024, 1024);
}

// Round 2
// 22697.221 us; speedup vs baseline: 1.2307x; 1.2307x over previous
//
#include <hip/hip_runtime.h>
#include <hip/hip_bf16.h>

typedef unsigned short u16;
typedef short  s16x4 __attribute__((ext_vector_type(4)));
typedef short  s16x8 __attribute__((ext_vector_type(8)));
typedef __bf16 bf16x8 __attribute__((ext_vector_type(8)));
typedef float  f32x4 __attribute__((ext_vector_type(4)));

__device__ __forceinline__ u16 f32_to_bf16(float f) {
  unsigned u = __builtin_bit_cast(unsigned, f);
  u += 0x7fffu + ((u >> 16) & 1u);
  return (u16)(u >> 16);
}
__device__ __forceinline__ float bf16_to_f32(u16 b) {
  unsigned u = ((unsigned)b) << 16;
  return __builtin_bit_cast(float, u);
}
__device__ __forceinline__ float sigmoidf_(float x) { return 1.f / (1.f + __expf(-x)); }
__device__ __forceinline__ float tanhf_(float x)    { return 1.f - 2.f / (__expf(2.f * x) + 1.f); }

__device__ __forceinline__ void load_lds16(const void* g, void* l) {
  __builtin_amdgcn_global_load_lds((const __attribute__((address_space(1))) void*)g,
                                   (__attribute__((address_space(3))) void*)l, 16, 0, 0);
}
__device__ __forceinline__ f32x4 mfma_bf16(bf16x8 a, bf16x8 b, f32x4 c) {
  return __builtin_amdgcn_mfma_f32_16x16x32_bf16(a, b, c, 0, 0, 0);
}

// device-scope relaxed load/store for barrier flags (bypass non-coherent per-XCD caches)
__device__ __forceinline__ unsigned ld_agent(const unsigned* p) {
  return __hip_atomic_load(p, __ATOMIC_RELAXED, __HIP_MEMORY_SCOPE_AGENT);
}
__device__ __forceinline__ void st_agent(unsigned* p, unsigned v) {
  __hip_atomic_store(p, v, __ATOMIC_RELAXED, __HIP_MEMORY_SCOPE_AGENT);
}

// ---------------- prep kernels ----------------

__global__ void cvt_f32_bf16_k(const float* __restrict__ in, u16* __restrict__ out, int n4) {
  int i = blockIdx.x * 256 + threadIdx.x;
  if (i < n4) {
    const float4 v = ((const float4*)in)[i];
    s16x4 o = { (short)f32_to_bf16(v.x), (short)f32_to_bf16(v.y),
                (short)f32_to_bf16(v.z), (short)f32_to_bf16(v.w) };
    *(s16x4*)&out[(size_t)i * 4] = o;
  }
}

__global__ void transpose_cvt_k(const float* __restrict__ src, u16* __restrict__ dst, int K, int N) {
  int lane = threadIdx.x & 63, wv = threadIdx.x >> 6;
  int n  = blockIdx.x * 64 + lane;
  int k0 = (blockIdx.y * 4 + wv) * 8;
  s16x8 o;
#pragma unroll
  for (int j = 0; j < 8; ++j)
    o[j] = (short)f32_to_bf16(src[(size_t)(k0 + j) * N + n]);
  *(s16x8*)&dst[(size_t)n * K + k0] = o;
}

__global__ void make_bcat_k(const float* bxi, const float* bxf, const float* bxc, const float* bxo,
                            const float* bhi, const float* bhf, const float* bhc, const float* bho,
                            float* bcat) {
  int i = blockIdx.x * 256 + threadIdx.x;  // 0..4095
  int g = i >> 10, h = i & 1023;
  float v;
  if (g == 0)      v = bxi[h] + bhi[h];
  else if (g == 1) v = bxf[h] + bhf[h];
  else if (g == 2) v = bxc[h] + bhc[h];
  else             v = bxo[h] + bho[h];
  bcat[i] = v;
}

__global__ void zero_bar_k(unsigned* p) {
  p[blockIdx.x * 256 + threadIdx.x] = 0u;
}

// ---------------- tiled bf16 GEMM:  C[M,N] = A[M,K] @ Bt[N,K]^T + bias ----------------

template<bool STORE_BF16>
__global__ __launch_bounds__(256, 2)
void gemm_bt(const u16* __restrict__ A, const u16* __restrict__ Bt,
             void* __restrict__ Cout, const float* __restrict__ bias,
             int M, int N, int K)
{
  __shared__ __align__(16) u16 As[128 * 64];
  __shared__ __align__(16) u16 Bs[128 * 64];
  const int tid  = threadIdx.x;
  const int lane = tid & 63;
  const int wv   = tid >> 6;
  const int ntile = blockIdx.x, mtile = blockIdx.y;
  const u16* Ab = A + (size_t)mtile * 128 * K;
  const u16* Bb = Bt + (size_t)ntile * 128 * K;

  const int r8   = lane >> 3;
  const int slot = lane & 7;
  const int cgk  = slot ^ r8;
  const int r = lane & 15;
  const int q = lane >> 4;
  const int mbase = (wv & 1) * 64;
  const int nbase = (wv >> 1) * 64;

  f32x4 acc[4][4];
#pragma unroll
  for (int i = 0; i < 4; ++i)
#pragma unroll
    for (int j = 0; j < 4; ++j) acc[i][j] = (f32x4){0.f, 0.f, 0.f, 0.f};

  for (int kb = 0; kb < K; kb += 64) {
    __syncthreads();
#pragma unroll
    for (int j = 0; j < 4; ++j) {
      const int row = wv * 32 + j * 8;
      load_lds16(Ab + (size_t)(row + r8) * K + kb + cgk * 8, &As[row * 64]);
      load_lds16(Bb + (size_t)(row + r8) * K + kb + cgk * 8, &Bs[row * 64]);
    }
    __syncthreads();
#pragma unroll
    for (int kk = 0; kk < 64; kk += 32) {
      const int cbase = (kk >> 3) + q;
      bf16x8 af[4], bf[4];
#pragma unroll
      for (int mi = 0; mi < 4; ++mi) {
        int rr = mbase + mi * 16 + r;
        af[mi] = *(const bf16x8*)&As[rr * 64 + (cbase ^ (rr & 7)) * 8];
      }
#pragma unroll
      for (int ni = 0; ni < 4; ++ni) {
        int rr = nbase + ni * 16 + r;
        bf[ni] = *(const bf16x8*)&Bs[rr * 64 + (cbase ^ (rr & 7)) * 8];
      }
#pragma unroll
      for (int mi = 0; mi < 4; ++mi)
#pragma unroll
        for (int ni = 0; ni < 4; ++ni)
          acc[mi][ni] = mfma_bf16(af[mi], bf[ni], acc[mi][ni]);
    }
  }

#pragma unroll
  for (int mi = 0; mi < 4; ++mi) {
#pragma unroll
    for (int ni = 0; ni < 4; ++ni) {
      const int col = ntile * 128 + nbase + ni * 16 + r;
      const float bv = bias[col];
#pragma unroll
      for (int t2 = 0; t2 < 4; ++t2) {
        const size_t rowg = (size_t)mtile * 128 + mbase + mi * 16 + q * 4 + t2;
        float v = acc[mi][ni][t2] + bv;
        if (STORE_BF16) ((u16*)Cout)[rowg * N + col] = f32_to_bf16(v);
        else            ((float*)Cout)[rowg * N + col] = v;
      }
    }
  }
}

// ---------------- persistent LSTM scan with custom fast grid barrier ----------------
// 256 WGs = 4 batch-blocks x 64 dim-blocks. Each WG: 16 batch rows x 16 h-dims.
// Barrier: padded per-WG arrive slots (stride 16 uints) + WG0 parallel poll + release flag.

__global__ __launch_bounds__(256, 1)
void lstm_scan(const u16* __restrict__ gates_x, u16* __restrict__ h_hist,
               const float* __restrict__ Whi, const float* __restrict__ Whf,
               const float* __restrict__ Whc, const float* __restrict__ Who, int S,
               unsigned* __restrict__ bar_arrive, unsigned* __restrict__ bar_release)
{
  extern __shared__ char smem[];
  u16*   Wt  = (u16*)smem;                     // [64][1032] bf16
  float* pre = (float*)(smem + 64 * 1032 * 2); // [4][16][16]
  const int tid = threadIdx.x, lane = tid & 63, wv = tid >> 6;
  const int wg = blockIdx.x;
  const int bblk = wg >> 6;
  const int dblk = wg & 63;
  const int dim0 = dblk << 4;
  const int d = tid & 15, b = tid >> 4;

  // load W_h slice -> LDS (one-time)
  {
    const int pr = tid >> 4;
    const float* Ws[4] = {Whi, Whf, Whc, Who};
#pragma unroll
    for (int g = 0; g < 4; ++g) {
      const float* W = Ws[g];
      for (int it = 0; it < 64; ++it) {
        int k = it * 16 + pr;
        float v = W[(size_t)k * 1024 + dim0 + d];
        Wt[(g * 16 + d) * 1032 + k] = f32_to_bf16(v);
      }
    }
  }
  // zero h_0 slice; c-state in register
  h_hist[(size_t)(bblk * 16 + b) * 1024 + dim0 + d] = 0;
  float c = 0.f;

  // prefetch xg for t=0 (gates_x ready by stream order)
  const u16* gx0 = gates_x + (size_t)(bblk * 16 + b) * 4096 + dim0 + d;
  float xg0 = bf16_to_f32(gx0[0]);
  float xg1 = bf16_to_f32(gx0[1024]);
  float xg2 = bf16_to_f32(gx0[2048]);
  float xg3 = bf16_to_f32(gx0[3072]);

  // ---- initial barrier (phase 1) ----
  {
    __threadfence();
    __syncthreads();
    if (wg == 0) {
      if (tid == 0) st_agent(bar_arrive, 1u);
      while (ld_agent(bar_arrive + tid * 16) < 1u) __builtin_amdgcn_s_sleep(2);
      __syncthreads();
      if (tid == 0) { __threadfence(); st_agent(bar_release, 1u); }
    } else {
      if (tid == 0) {
        st_agent(bar_arrive + wg * 16, 1u);
        while (ld_agent(bar_release) < 1u) __builtin_amdgcn_s_sleep(4);
      }
      __syncthreads();
    }
    __threadfence();
  }

  const int r = lane & 15, q = lane >> 4;
  const u16* Brow = Wt + (wv * 16 + r) * 1032 + q * 8;

  for (int t = 0; t < S; ++t) {
    // wave wv computes gate wv: [16 batch x 16 dim] = h_t[16x1024] @ Wt[16 cols]
    const u16* Arow = h_hist + (size_t)t * 65536 + (size_t)(bblk * 16 + r) * 1024 + q * 8;
    f32x4 a0 = {0.f, 0.f, 0.f, 0.f}, a1 = a0, a2 = a0, a3 = a0;
#pragma unroll
    for (int k = 0; k < 1024; k += 128) {
      a0 = mfma_bf16(*(const bf16x8*)(Arow + k),      *(const bf16x8*)(Brow + k),      a0);
      a1 = mfma_bf16(*(const bf16x8*)(Arow + k + 32), *(const bf16x8*)(Brow + k + 32), a1);
      a2 = mfma_bf16(*(const bf16x8*)(Arow + k + 64), *(const bf16x8*)(Brow + k + 64), a2);
      a3 = mfma_bf16(*(const bf16x8*)(Arow + k + 96), *(const bf16x8*)(Brow + k + 96), a3);
    }
    f32x4 accv = (a0 + a1) + (a2 + a3);
#pragma unroll
    for (int t2 = 0; t2 < 4; ++t2)
      pre[wv * 256 + (q * 4 + t2) * 16 + r] = accv[t2];
    __syncthreads();

    float pi = pre[0 * 256 + b * 16 + d] + xg0;
    float pf = pre[1 * 256 + b * 16 + d] + xg1;
    float pc = pre[2 * 256 + b * 16 + d] + xg2;
    float po = pre[3 * 256 + b * 16 + d] + xg3;
    float ig = sigmoidf_(pi);
    float fg = sigmoidf_(pf);
    float gg = tanhf_(pc);
    float og = sigmoidf_(po);
    c = fg * c + ig * gg;
    float h = og * tanhf_(c);
    h_hist[(size_t)(t + 1) * 65536 + (size_t)(bblk * 16 + b) * 1024 + dim0 + d] = f32_to_bf16(h);

    if (t + 1 < S) {
      const unsigned phase = (unsigned)(t + 2);
      __threadfence();        // release: drain h store + wb L2
      __syncthreads();        // whole WG fenced

      // prefetch next step's x-gates into registers during the barrier wait
      const u16* gx = gates_x + (size_t)((t + 1) * 64 + bblk * 16 + b) * 4096 + dim0 + d;
      u16 n0 = gx[0], n1 = gx[1024], n2 = gx[2048], n3 = gx[3072];

      if (wg == 0) {
        if (tid == 0) st_agent(bar_arrive, phase);
        while (ld_agent(bar_arrive + tid * 16) < phase) __builtin_amdgcn_s_sleep(2);
        __syncthreads();
        if (tid == 0) { __threadfence(); st_agent(bar_release, phase); }
      } else {
        if (tid == 0) {
          st_agent(bar_arrive + wg * 16, phase);
          while (ld_agent(bar_release) < phase) __builtin_amdgcn_s_sleep(4);
        }
        __syncthreads();
      }
      __threadfence();        // acquire: invalidate caches before reading new h

      xg0 = bf16_to_f32(n0); xg1 = bf16_to_f32(n1);
      xg2 = bf16_to_f32(n2); xg3 = bf16_to_f32(n3);
    }
  }
}

// ---------------- launcher ----------------

extern "C" void kernel_launch(void* const* d_in, const int* in_sizes, int n_in,
                              void* d_out, int out_size, void* d_ws, size_t ws_size,
                              hipStream_t stream)
{
  const float* x   = (const float*)d_in[0];
  const float* Wxi = (const float*)d_in[1];
  const float* bxi = (const float*)d_in[2];
  const float* Wxf = (const float*)d_in[3];
  const float* bxf = (const float*)d_in[4];
  const float* Wxc = (const float*)d_in[5];
  const float* bxc = (const float*)d_in[6];
  const float* Wxo = (const float*)d_in[7];
  const float* bxo = (const float*)d_in[8];
  const float* Whi = (const float*)d_in[9];
  const float* bhi = (const float*)d_in[10];
  const float* Whf = (const float*)d_in[11];
  const float* bhf = (const float*)d_in[12];
  const float* Whc = (const float*)d_in[13];
  const float* bhc = (const float*)d_in[14];
  const float* Who = (const float*)d_in[15];
  const float* bho = (const float*)d_in[16];
  const float* Why = (const float*)d_in[17];
  const float* bhy = (const float*)d_in[18];

  char* ws = (char*)d_ws;
  u16*   x_bf   = (u16*)(ws);                 //  67,108,864 B (reused: first 32 KB = barrier after gemm1)
  u16*   WcatT  = (u16*)(ws + 67108864);      //   8,388,608 B  [4096][1024]
  u16*   WhyT   = (u16*)(ws + 75497472);      //   2,097,152 B  [1024][1024]
  float* bcat   = (float*)(ws + 77594624);    //      16,384 B
  u16*   gatesx = (u16*)(ws + 77611008);      // 268,435,456 B  [32768][4096]
  u16*   hhist  = (u16*)(ws + 346046464);     //  67,239,936 B  [513][64][1024]
  unsigned* bar_arrive  = (unsigned*)ws;      // 256 slots, stride 16 uints (x_bf dead by then)
  unsigned* bar_release = (unsigned*)ws + 4096;

  // prep: casts + transposes + fused bias
  cvt_f32_bf16_k<<<32768, 256, 0, stream>>>(x, x_bf, 8388608);
  transpose_cvt_k<<<dim3(16, 32), 256, 0, stream>>>(Wxi, WcatT + 0 * 1048576, 1024, 1024);
  transpose_cvt_k<<<dim3(16, 32), 256, 0, stream>>>(Wxf, WcatT + 1 * 1048576, 1024, 1024);
  transpose_cvt_k<<<dim3(16, 32), 256, 0, stream>>>(Wxc, WcatT + 2 * 1048576, 1024, 1024);
  transpose_cvt_k<<<dim3(16, 32), 256, 0, stream>>>(Wxo, WcatT + 3 * 1048576, 1024, 1024);
  transpose_cvt_k<<<dim3(16, 32), 256, 0, stream>>>(Why, WhyT, 1024, 1024);
  make_bcat_k<<<16, 256, 0, stream>>>(bxi, bxf, bxc, bxo, bhi, bhf, bhc, bho, bcat);

  // phase 1: gates_x = x @ [Wxi|Wxf|Wxc|Wxo] + (b_x + b_h)
  gemm_bt<true><<<dim3(32, 256), 256, 0, stream>>>(x_bf, WcatT, (void*)gatesx, bcat, 32768, 4096, 1024);

  // zero barrier state (x_bf region is dead after gemm1)
  zero_bar_k<<<32, 256, 0, stream>>>((unsigned*)ws);

  // phase 2: persistent cooperative scan with custom barrier
  (void)hipFuncSetAttribute((const void*)lstm_scan, hipFuncAttributeMaxDynamicSharedMemorySize, 136192);
  int S = 512;
  void* args[] = {(void*)&gatesx, (void*)&hhist, (void*)&Whi, (void*)&Whf, (void*)&Whc, (void*)&Who,
                  (void*)&S, (void*)&bar_arrive, (void*)&bar_release};
  (void)hipLaunchCooperativeKernel((void*)lstm_scan, dim3(256), dim3(256), args, 136192, stream);

  // phase 3: y = h_{1..S} @ W_hy + b_hy  (fp32 out)
  gemm_bt<false><<<dim3(8, 256), 256, 0, stream>>>(hhist + 65536, WhyT, d_out, bhy, 32768, 1024, 1024);
}

// Round 3
// 3820.085 us; speedup vs baseline: 7.3123x; 5.9415x over previous
//
#include <hip/hip_runtime.h>
#include <hip/hip_bf16.h>

typedef unsigned short u16;
typedef short  s16x4 __attribute__((ext_vector_type(4)));
typedef short  s16x8 __attribute__((ext_vector_type(8)));
typedef __bf16 bf16x8 __attribute__((ext_vector_type(8)));
typedef float  f32x4 __attribute__((ext_vector_type(4)));
typedef unsigned uint32x4 __attribute__((ext_vector_type(4)));

__device__ __forceinline__ u16 f32_to_bf16(float f) {
  unsigned u = __builtin_bit_cast(unsigned, f);
  u += 0x7fffu + ((u >> 16) & 1u);
  return (u16)(u >> 16);
}
__device__ __forceinline__ float bf16_to_f32(u16 b) {
  unsigned u = ((unsigned)b) << 16;
  return __builtin_bit_cast(float, u);
}
__device__ __forceinline__ float sigmoidf_(float x) { return 1.f / (1.f + __expf(-x)); }
__device__ __forceinline__ float tanhf_(float x)    { return 1.f - 2.f / (__expf(2.f * x) + 1.f); }

__device__ __forceinline__ void load_lds16(const void* g, void* l) {
  __builtin_amdgcn_global_load_lds((const __attribute__((address_space(1))) void*)g,
                                   (__attribute__((address_space(3))) void*)l, 16, 0, 0);
}
__device__ __forceinline__ f32x4 mfma_bf16(bf16x8 a, bf16x8 b, f32x4 c) {
  return __builtin_amdgcn_mfma_f32_16x16x32_bf16(a, b, c, 0, 0, 0);
}

// agent-scope relaxed atomics: compile to sc0/sc1 (point-of-coherence) ops, NO fences
__device__ __forceinline__ unsigned ld_agent(const unsigned* p) {
  return __hip_atomic_load(p, __ATOMIC_RELAXED, __HIP_MEMORY_SCOPE_AGENT);
}
__device__ __forceinline__ void st_agent(unsigned* p, unsigned v) {
  __hip_atomic_store(p, v, __ATOMIC_RELAXED, __HIP_MEMORY_SCOPE_AGENT);
}

// ---------------- prep kernels ----------------

__global__ void cvt_f32_bf16_k(const float* __restrict__ in, u16* __restrict__ out, int n4) {
  int i = blockIdx.x * 256 + threadIdx.x;
  if (i < n4) {
    const float4 v = ((const float4*)in)[i];
    s16x4 o = { (short)f32_to_bf16(v.x), (short)f32_to_bf16(v.y),
                (short)f32_to_bf16(v.z), (short)f32_to_bf16(v.w) };
    *(s16x4*)&out[(size_t)i * 4] = o;
  }
}

// dst[n][k] = src[k][n]  (fp32 -> bf16)
__global__ void transpose_cvt_k(const float* __restrict__ src, u16* __restrict__ dst, int K, int N) {
  int lane = threadIdx.x & 63, wv = threadIdx.x >> 6;
  int n  = blockIdx.x * 64 + lane;
  int k0 = (blockIdx.y * 4 + wv) * 8;
  s16x8 o;
#pragma unroll
  for (int j = 0; j < 8; ++j)
    o[j] = (short)f32_to_bf16(src[(size_t)(k0 + j) * N + n]);
  *(s16x8*)&dst[(size_t)n * K + k0] = o;
}

__global__ void make_bcat_k(const float* bxi, const float* bxf, const float* bxc, const float* bxo,
                            const float* bhi, const float* bhf, const float* bhc, const float* bho,
                            float* bcat) {
  int i = blockIdx.x * 256 + threadIdx.x;  // 0..4095
  int g = i >> 10, h = i & 1023;
  float v;
  if (g == 0)      v = bxi[h] + bhi[h];
  else if (g == 1) v = bxf[h] + bhf[h];
  else if (g == 2) v = bxc[h] + bhc[h];
  else             v = bxo[h] + bho[h];
  bcat[i] = v;
}

__global__ void zero_bar_k(unsigned* p) {
  p[blockIdx.x * 256 + threadIdx.x] = 0u;
}

// ---------------- tiled bf16 GEMM:  C[M,N] = A[M,K] @ Bt[N,K]^T + bias ----------------

template<bool STORE_BF16>
__global__ __launch_bounds__(256, 2)
void gemm_bt(const u16* __restrict__ A, const u16* __restrict__ Bt,
             void* __restrict__ Cout, const float* __restrict__ bias,
             int M, int N, int K)
{
  __shared__ __align__(16) u16 As[128 * 64];
  __shared__ __align__(16) u16 Bs[128 * 64];
  const int tid  = threadIdx.x;
  const int lane = tid & 63;
  const int wv   = tid >> 6;
  const int ntile = blockIdx.x, mtile = blockIdx.y;
  const u16* Ab = A + (size_t)mtile * 128 * K;
  const u16* Bb = Bt + (size_t)ntile * 128 * K;

  const int r8   = lane >> 3;
  const int slot = lane & 7;
  const int cgk  = slot ^ r8;
  const int r = lane & 15;
  const int q = lane >> 4;
  const int mbase = (wv & 1) * 64;
  const int nbase = (wv >> 1) * 64;

  f32x4 acc[4][4];
#pragma unroll
  for (int i = 0; i < 4; ++i)
#pragma unroll
    for (int j = 0; j < 4; ++j) acc[i][j] = (f32x4){0.f, 0.f, 0.f, 0.f};

  for (int kb = 0; kb < K; kb += 64) {
    __syncthreads();
#pragma unroll
    for (int j = 0; j < 4; ++j) {
      const int row = wv * 32 + j * 8;
      load_lds16(Ab + (size_t)(row + r8) * K + kb + cgk * 8, &As[row * 64]);
      load_lds16(Bb + (size_t)(row + r8) * K + kb + cgk * 8, &Bs[row * 64]);
    }
    __syncthreads();
#pragma unroll
    for (int kk = 0; kk < 64; kk += 32) {
      const int cbase = (kk >> 3) + q;
      bf16x8 af[4], bf[4];
#pragma unroll
      for (int mi = 0; mi < 4; ++mi) {
        int rr = mbase + mi * 16 + r;
        af[mi] = *(const bf16x8*)&As[rr * 64 + (cbase ^ (rr & 7)) * 8];
      }
#pragma unroll
      for (int ni = 0; ni < 4; ++ni) {
        int rr = nbase + ni * 16 + r;
        bf[ni] = *(const bf16x8*)&Bs[rr * 64 + (cbase ^ (rr & 7)) * 8];
      }
#pragma unroll
      for (int mi = 0; mi < 4; ++mi)
#pragma unroll
        for (int ni = 0; ni < 4; ++ni)
          acc[mi][ni] = mfma_bf16(af[mi], bf[ni], acc[mi][ni]);
    }
  }

#pragma unroll
  for (int mi = 0; mi < 4; ++mi) {
#pragma unroll
    for (int ni = 0; ni < 4; ++ni) {
      const int col = ntile * 128 + nbase + ni * 16 + r;
      const float bv = bias[col];
#pragma unroll
      for (int t2 = 0; t2 < 4; ++t2) {
        const size_t rowg = (size_t)mtile * 128 + mbase + mi * 16 + q * 4 + t2;
        float v = acc[mi][ni][t2] + bv;
        if (STORE_BF16) ((u16*)Cout)[rowg * N + col] = f32_to_bf16(v);
        else            ((float*)Cout)[rowg * N + col] = v;
      }
    }
  }
}

// ---------------- persistent LSTM scan, fence-free ----------------
// 256 WGs = 4 independent batch-groups x 64 dim-blocks. WG covers 16 batch x 16 h-dims.
// W_h slice lives ENTIRELY in VGPRs (k-split over 4 waves: wave wv holds k in
// [wv*256, wv*256+256) for all 4 gates x 16 dims = 32 bf16x8 fragments).
// h exchanged via agent-scope (sc0sc1) atomics -> no buffer_inv/wbl2 anywhere.
// Barrier: all-to-all among the 64 WGs of a batch group; wave0 lane l polls member l.

__global__ __launch_bounds__(256, 1)
void lstm_scan(const u16* __restrict__ gates_x, u16* __restrict__ h_hist,
               const u16* __restrict__ WhT, int S, unsigned* __restrict__ bar)
{
  __shared__ float pre[4096];  // [wv][gate][row(b)*16+col(d)]
  const int tid = threadIdx.x, lane = tid & 63, wv = tid >> 6;
  const int wg = blockIdx.x;
  const int bblk = wg >> 6;
  const int dblk = wg & 63;
  const int dim0 = dblk << 4;
  const int d = tid & 15, b = tid >> 4;
  const int r = lane & 15, q = lane >> 4;

  // ---- one-time: W_h fragments -> registers (plain cached loads; WhT stable) ----
  bf16x8 wfr[4][8];
#pragma unroll
  for (int ct = 0; ct < 4; ++ct) {
#pragma unroll
    for (int ks = 0; ks < 8; ++ks) {
      const size_t row = (size_t)ct * 1024 + dim0 + r;
      wfr[ct][ks] = *(const bf16x8*)(WhT + row * 1024 + wv * 256 + ks * 32 + q * 8);
    }
  }

  // A fragments: h_t rows (batch) x k. t=0: h_0 = 0 -> zero fragments, no load.
  bf16x8 afr[8];
#pragma unroll
  for (int ks = 0; ks < 8; ++ks) afr[ks] = __builtin_bit_cast(bf16x8, (uint32x4){0u,0u,0u,0u});

  const unsigned* h32 = (const unsigned*)h_hist;
  unsigned* h32w = (unsigned*)h_hist;
  const unsigned abase = (unsigned)((bblk * 16 + r) * 512 + wv * 128 + q * 4);

  // x-gate preactivations for t=0 (plain cached loads)
  const u16* gx0 = gates_x + (size_t)(bblk * 16 + b) * 4096 + dim0 + d;
  float xg0 = bf16_to_f32(gx0[0]);
  float xg1 = bf16_to_f32(gx0[1024]);
  float xg2 = bf16_to_f32(gx0[2048]);
  float xg3 = bf16_to_f32(gx0[3072]);

  float c = 0.f;

  for (int t = 0; t < S; ++t) {
    // gate GEMM partials: wave wv covers k-quarter wv, all 4 gate tiles
    f32x4 acc[4];
#pragma unroll
    for (int ct = 0; ct < 4; ++ct) acc[ct] = (f32x4){0.f, 0.f, 0.f, 0.f};
#pragma unroll
    for (int ks = 0; ks < 8; ++ks) {
#pragma unroll
      for (int ct = 0; ct < 4; ++ct)
        acc[ct] = mfma_bf16(afr[ks], wfr[ct][ks], acc[ct]);
    }
    // exchange partials through LDS
#pragma unroll
    for (int ct = 0; ct < 4; ++ct)
#pragma unroll
      for (int t2 = 0; t2 < 4; ++t2)
        pre[wv * 1024 + ct * 256 + (q * 4 + t2) * 16 + r] = acc[ct][t2];
    __syncthreads();

    float pi = xg0, pf = xg1, pc = xg2, po = xg3;
#pragma unroll
    for (int w4 = 0; w4 < 4; ++w4) {
      pi += pre[w4 * 1024 + 0 * 256 + tid];
      pf += pre[w4 * 1024 + 1 * 256 + tid];
      pc += pre[w4 * 1024 + 2 * 256 + tid];
      po += pre[w4 * 1024 + 3 * 256 + tid];
    }
    float ig = sigmoidf_(pi);
    float fg = sigmoidf_(pf);
    float gg = tanhf_(pc);
    float og = sigmoidf_(po);
    c = fg * c + ig * gg;
    float h = og * tanhf_(c);

    // pack adjacent-dim pair -> u32, coherent write-through store (half the threads)
    unsigned hv = (unsigned)f32_to_bf16(h);
    unsigned nb = (unsigned)__shfl_down((int)hv, 1, 64);
    if ((d & 1) == 0) {
      unsigned idx = (unsigned)((t + 1) * 32768 + (bblk * 16 + b) * 512 + ((dim0 + d) >> 1));
      st_agent(h32w + idx, hv | (nb << 16));
    }

    if (t + 1 < S) {
      const unsigned phase = (unsigned)(t + 1);
      __builtin_amdgcn_s_waitcnt(0);   // h stores acked at coherence point
      __syncthreads();                 // all waves drained
      if (tid == 0) st_agent(bar + wg * 16, phase);

      // prefetch next step's x-gates (plain cached) while barrier settles
      const u16* gx = gates_x + (size_t)((t + 1) * 64 + bblk * 16 + b) * 4096 + dim0 + d;
      u16 n0 = gx[0], n1 = gx[1024], n2 = gx[2048], n3 = gx[3072];

      if (tid < 64) {
        const unsigned* fp = bar + (bblk * 64 + tid) * 16;
        while (ld_agent(fp) < phase) { }
      }
      __atomic_signal_fence(__ATOMIC_ACQ_REL);
      __syncthreads();

      // load h_{t+1} fragments coherently (bypass stale L1/L2)
      const unsigned* hp = h32 + (size_t)(t + 1) * 32768 + abase;
#pragma unroll
      for (int ks = 0; ks < 8; ++ks) {
        uint32x4 w4v = { ld_agent(hp + ks * 16 + 0), ld_agent(hp + ks * 16 + 1),
                         ld_agent(hp + ks * 16 + 2), ld_agent(hp + ks * 16 + 3) };
        afr[ks] = __builtin_bit_cast(bf16x8, w4v);
      }
      xg0 = bf16_to_f32(n0); xg1 = bf16_to_f32(n1);
      xg2 = bf16_to_f32(n2); xg3 = bf16_to_f32(n3);
    }
  }
}

// ---------------- launcher ----------------

extern "C" void kernel_launch(void* const* d_in, const int* in_sizes, int n_in,
                              void* d_out, int out_size, void* d_ws, size_t ws_size,
                              hipStream_t stream)
{
  const float* x   = (const float*)d_in[0];
  const float* Wxi = (const float*)d_in[1];
  const float* bxi = (const float*)d_in[2];
  const float* Wxf = (const float*)d_in[3];
  const float* bxf = (const float*)d_in[4];
  const float* Wxc = (const float*)d_in[5];
  const float* bxc = (const float*)d_in[6];
  const float* Wxo = (const float*)d_in[7];
  const float* bxo = (const float*)d_in[8];
  const float* Whi = (const float*)d_in[9];
  const float* bhi = (const float*)d_in[10];
  const float* Whf = (const float*)d_in[11];
  const float* bhf = (const float*)d_in[12];
  const float* Whc = (const float*)d_in[13];
  const float* bhc = (const float*)d_in[14];
  const float* Who = (const float*)d_in[15];
  const float* bho = (const float*)d_in[16];
  const float* Why = (const float*)d_in[17];
  const float* bhy = (const float*)d_in[18];

  char* ws = (char*)d_ws;
  u16*   x_bf   = (u16*)(ws);                 // 67,108,864 B (dead after gemm1 -> reused below)
  u16*   WcatT  = (u16*)(ws + 67108864);      //  8,388,608 B  [4096][1024]
  u16*   WhyT   = (u16*)(ws + 75497472);      //  2,097,152 B  [1024][1024]
  float* bcat   = (float*)(ws + 77594624);    //     16,384 B
  u16*   gatesx = (u16*)(ws + 77611008);      // 268,435,456 B [32768][4096]
  u16*   hhist  = (u16*)(ws + 346046464);     // 67,239,936 B  [513][64][1024]
  // reuse of dead x_bf region (after gemm1):
  u16*      WhT = (u16*)ws;                   //  8,388,608 B  [4096][1024] bf16 W_h^T
  unsigned* bar = (unsigned*)(ws + 16777216); //     16,384 B  barrier flags

  // prep: casts + transposes + fused bias
  cvt_f32_bf16_k<<<32768, 256, 0, stream>>>(x, x_bf, 8388608);
  transpose_cvt_k<<<dim3(16, 32), 256, 0, stream>>>(Wxi, WcatT + 0 * 1048576, 1024, 1024);
  transpose_cvt_k<<<dim3(16, 32), 256, 0, stream>>>(Wxf, WcatT + 1 * 1048576, 1024, 1024);
  transpose_cvt_k<<<dim3(16, 32), 256, 0, stream>>>(Wxc, WcatT + 2 * 1048576, 1024, 1024);
  transpose_cvt_k<<<dim3(16, 32), 256, 0, stream>>>(Wxo, WcatT + 3 * 1048576, 1024, 1024);
  transpose_cvt_k<<<dim3(16, 32), 256, 0, stream>>>(Why, WhyT, 1024, 1024);
  make_bcat_k<<<16, 256, 0, stream>>>(bxi, bxf, bxc, bxo, bhi, bhf, bhc, bho, bcat);

  // phase 1: gates_x = x @ [Wxi|Wxf|Wxc|Wxo] + (b_x + b_h)   (consumes x_bf)
  gemm_bt<true><<<dim3(32, 256), 256, 0, stream>>>(x_bf, WcatT, (void*)gatesx, bcat, 32768, 4096, 1024);

  // now x_bf region is dead: build W_h^T there + zero barrier flags
  transpose_cvt_k<<<dim3(16, 32), 256, 0, stream>>>(Whi, WhT + 0 * 1048576, 1024, 1024);
  transpose_cvt_k<<<dim3(16, 32), 256, 0, stream>>>(Whf, WhT + 1 * 1048576, 1024, 1024);
  transpose_cvt_k<<<dim3(16, 32), 256, 0, stream>>>(Whc, WhT + 2 * 1048576, 1024, 1024);
  transpose_cvt_k<<<dim3(16, 32), 256, 0, stream>>>(Who, WhT + 3 * 1048576, 1024, 1024);
  zero_bar_k<<<16, 256, 0, stream>>>(bar);

  // phase 2: persistent cooperative scan (fence-free barriers)
  int S = 512;
  void* args[] = {(void*)&gatesx, (void*)&hhist, (void*)&WhT, (void*)&S, (void*)&bar};
  (void)hipLaunchCooperativeKernel((void*)lstm_scan, dim3(256), dim3(256), args, 0, stream);

  // phase 3: y = h_{1..S} @ W_hy + b_hy  (fp32 out)
  gemm_bt<false><<<dim3(8, 256), 256, 0, stream>>>(hhist + 65536, WhyT, d_out, bhy, 32768, 1024, 1024);
}